// Round 7
// baseline (68.472 us; speedup 1.0000x reference)
//
#include <hip/hip_runtime.h>
#include <hip/hip_bf16.h>

// Problem constants
#define D_DIM 512
#define K_DIM 512
#define B_C   64

// Weight-resident config: one block per (segment, ct); block loops row-tiles.
#define BM 128
#define BN 128
#define BK 64
#define KSTEPS 8             // D_DIM / BK
#define ROWT 8               // LMAX / BM (max row-tiles per segment)
#define COLT 4               // K_DIM / BN
#define NWG  (B_C * COLT)    // 256 blocks, divisible by 8 XCDs, 1 per CU

typedef __attribute__((ext_vector_type(8))) short bf16x8;
typedef __attribute__((ext_vector_type(4))) float f32x4;

__device__ __forceinline__ short f2bf(float f) {
    union { __hip_bfloat16 h; short s; } u;
    u.h = __float2bfloat16(f);
    return u.s;
}

// A swizzle (R3-validated, zero conflicts): rows are 128B (8 x 16B slots).
__device__ __forceinline__ int fA(int r) { return (r & 7) ^ ((r >> 2) & 7); }
// W swizzle: rows are 1024B (64 x 16B slots). 4-bit XOR spreads both the
// stride-4-row write phases and stride-1-row read phases across banks.
__device__ __forceinline__ int fW(int r) { return (r & 15) ^ ((r >> 2) & 15); }

__global__ __launch_bounds__(512, 2) void jbmm_kernel(
    const int* __restrict__ offsets,   // B+1
    const int* __restrict__ index,     // B
    const float* __restrict__ jagged,  // T x D
    const float* __restrict__ weight,  // NW x D x K
    const float* __restrict__ bias,    // NW x K
    float* __restrict__ out)           // T x K
{
    // 128 KiB weight slice (transposed, bf16, swizzled) + 2x16 KiB A buffers
    __shared__ short Ws[BN * D_DIM];       // [n:128][k-slots], row stride 1024 B
    __shared__ short As[2][BM * BK];       // [row:128][k-slots], row stride 128 B

    // XCD chunk swizzle (256 % 8 == 0 -> bijective)
    const int bidRaw = blockIdx.x;
    const int bid = (bidRaw & 7) * (NWG / 8) + (bidRaw >> 3);
    const int b  = bid >> 2;
    const int ct = bid & 3;

    const int start = offsets[b];
    const int end   = offsets[b + 1];
    const int idxw  = index[b];
    const int n0    = ct * BN;
    const float* W  = weight + (size_t)idxw * D_DIM * K_DIM;

    const int tid  = threadIdx.x;
    const int lane = tid & 63;
    const int wid  = tid >> 6;   // 0..7
    const int wr   = wid >> 2;   // 0..1: 64 rows each
    const int wc   = wid & 3;    // 0..3: 32 cols each
    const int lr   = lane & 15;
    const int lg   = lane >> 4;

    // ---- W prologue: stage full 512x128 slice, f32 -> bf16 transposed ----
    {
        const int nq = tid & 31;   // n-quad: rows 4*nq..+3
        const int kg = tid >> 5;   // 0..15: k-rows kg*8..+7 per pass
        for (int p = 0; p < 4; ++p) {
            const int kbase = p * 128;
            f32x4 wv[8];
#pragma unroll
            for (int j = 0; j < 8; ++j)
                wv[j] = *reinterpret_cast<const f32x4*>(
                    &W[(size_t)(kbase + kg * 8 + j) * K_DIM + n0 + nq * 4]);
#pragma unroll
            for (int np = 0; np < 4; ++np) {
                const int row = nq * 4 + np;
                bf16x8 w8;
                w8[0] = f2bf(wv[0][np]); w8[1] = f2bf(wv[1][np]);
                w8[2] = f2bf(wv[2][np]); w8[3] = f2bf(wv[3][np]);
                w8[4] = f2bf(wv[4][np]); w8[5] = f2bf(wv[5][np]);
                w8[6] = f2bf(wv[6][np]); w8[7] = f2bf(wv[7][np]);
                const int sp = (p * 16 + kg) ^ fW(row);
                *reinterpret_cast<bf16x8*>((char*)Ws + row * 1024 + sp * 16) = w8;
            }
        }
    }

    float bias_v[2];
#pragma unroll
    for (int ni = 0; ni < 2; ++ni)
        bias_v[ni] = bias[(size_t)idxw * K_DIM + n0 + wc * 32 + ni * 16 + lr];

    asm volatile("s_waitcnt lgkmcnt(0)" ::: "memory");
    __builtin_amdgcn_s_barrier();
    asm volatile("" ::: "memory");

    // ---- A staging maps (512 threads) ----
    const int arow  = tid >> 2;  // 0..127
    const int acol4 = tid & 3;   // 0..3: 16 consecutive floats each

    f32x4 aR[4];

#define LOADA(k0_)                                                          \
    {                                                                       \
        if (arow < rows) {                                                  \
            const float* p = &jagged[(size_t)(m0 + arow) * D_DIM + (k0_) + acol4 * 16]; \
            _Pragma("unroll")                                               \
            for (int j = 0; j < 4; ++j)                                     \
                aR[j] = *reinterpret_cast<const f32x4*>(p + 4 * j);         \
        } else {                                                            \
            _Pragma("unroll")                                               \
            for (int j = 0; j < 4; ++j)                                     \
                aR[j] = (f32x4){0.f, 0.f, 0.f, 0.f};                        \
        }                                                                   \
    }

#define CVTSTORE_A(c_)                                                      \
    {                                                                       \
        _Pragma("unroll")                                                   \
        for (int j2 = 0; j2 < 2; ++j2) {                                    \
            bf16x8 w8;                                                      \
            w8[0] = f2bf(aR[2*j2][0]);   w8[1] = f2bf(aR[2*j2][1]);         \
            w8[2] = f2bf(aR[2*j2][2]);   w8[3] = f2bf(aR[2*j2][3]);         \
            w8[4] = f2bf(aR[2*j2+1][0]); w8[5] = f2bf(aR[2*j2+1][1]);       \
            w8[6] = f2bf(aR[2*j2+1][2]); w8[7] = f2bf(aR[2*j2+1][3]);       \
            const int sp = (acol4 * 2 + j2) ^ fA(arow);                     \
            *reinterpret_cast<bf16x8*>((char*)&As[c_][0] + arow * 128 + sp * 16) = w8; \
        }                                                                   \
    }

#define COMPUTE(c_, t_)                                                     \
    {                                                                       \
        __builtin_amdgcn_s_setprio(1);                                      \
        _Pragma("unroll")                                                   \
        for (int kh = 0; kh < 2; ++kh) {                                    \
            bf16x8 af[4], bfr[2];                                           \
            _Pragma("unroll")                                               \
            for (int mi = 0; mi < 4; ++mi) {                                \
                const int row = wr * 64 + mi * 16 + lr;                     \
                const int sp = (kh * 4 + lg) ^ fA(row);                     \
                af[mi] = *reinterpret_cast<bf16x8*>(                        \
                    (char*)&As[c_][0] + row * 128 + sp * 16);               \
            }                                                               \
            _Pragma("unroll")                                               \
            for (int ni = 0; ni < 2; ++ni) {                                \
                const int row = wc * 32 + ni * 16 + lr;                     \
                const int sp = ((t_) * 8 + kh * 4 + lg) ^ fW(row);          \
                bfr[ni] = *reinterpret_cast<bf16x8*>(                       \
                    (char*)Ws + row * 1024 + sp * 16);                      \
            }                                                               \
            _Pragma("unroll")                                               \
            for (int mi = 0; mi < 4; ++mi)                                  \
                _Pragma("unroll")                                           \
                for (int ni = 0; ni < 2; ++ni)                              \
                    acc[mi][ni] = __builtin_amdgcn_mfma_f32_16x16x32_bf16(  \
                        af[mi], bfr[ni], acc[mi][ni], 0, 0, 0);             \
        }                                                                   \
        __builtin_amdgcn_s_setprio(0);                                      \
    }

#define BARRIER_LDS()                                                       \
    {                                                                       \
        asm volatile("s_waitcnt lgkmcnt(0)" ::: "memory");                  \
        __builtin_amdgcn_s_barrier();                                       \
        asm volatile("" ::: "memory");                                      \
    }

    // ---- row-tile loop: W stays resident, stream A ----
    for (int rt = 0; rt < ROWT; ++rt) {
        const int m0 = start + rt * BM;
        if (m0 >= end) break;              // uniform: later tiles empty too
        const int rows = (end - m0) < BM ? (end - m0) : BM;

        f32x4 acc[4][2];
#pragma unroll
        for (int mi = 0; mi < 4; ++mi)
#pragma unroll
            for (int ni = 0; ni < 2; ++ni)
                acc[mi][ni] = (f32x4){0.f, 0.f, 0.f, 0.f};

        LOADA(0);
        CVTSTORE_A(0);
        BARRIER_LDS();

#pragma unroll
        for (int t = 0; t < KSTEPS; ++t) {
            if (t + 1 < KSTEPS) LOADA((t + 1) * BK);   // in flight over COMPUTE
            COMPUTE(t & 1, t);
            if (t + 1 < KSTEPS) {
                CVTSTORE_A((t + 1) & 1);               // vmcnt wait covered above
                BARRIER_LDS();
            }
        }

        // epilogue: C/D layout col=lane&15, row=(lane>>4)*4+r
#pragma unroll
        for (int mi = 0; mi < 4; ++mi) {
            const int rbase = wr * 64 + mi * 16 + lg * 4;
#pragma unroll
            for (int r = 0; r < 4; ++r) {
                const int rr = rbase + r;
                if (rr < rows) {
#pragma unroll
                    for (int ni = 0; ni < 2; ++ni)
                        out[(size_t)(m0 + rr) * K_DIM + n0 + wc * 32 + ni * 16 + lr] =
                            acc[mi][ni][r] + bias_v[ni];
                }
            }
        }
    }
}

extern "C" void kernel_launch(void* const* d_in, const int* in_sizes, int n_in,
                              void* d_out, int out_size, void* d_ws, size_t ws_size,
                              hipStream_t stream) {
    const int*   offsets = (const int*)d_in[1];
    const int*   index   = (const int*)d_in[2];
    const float* jagged  = (const float*)d_in[3];
    const float* weight  = (const float*)d_in[4];
    const float* bias    = (const float*)d_in[5];
    float*       out     = (float*)d_out;

    dim3 grid(NWG);    // 256 blocks = 1 per CU (160 KiB LDS each)
    dim3 block(512);
    hipLaunchKernelGGL(jbmm_kernel, grid, block, 0, stream,
                       offsets, index, jagged, weight, bias, out);
}